// Round 4
// baseline (245.763 us; speedup 1.0000x reference)
//
#include <hip/hip_runtime.h>
#include <math.h>

#define BB 2
#define LL 2048
#define DD 1024
#define HH 16
#define DHD 64
#define NT (BB*LL)
#define D3 (3*DD)
#define D2 (2*DD)

typedef __bf16 bf16x8 __attribute__((ext_vector_type(8)));
typedef float  f32x4  __attribute__((ext_vector_type(4)));

__device__ __forceinline__ f32x4 mfma16(bf16x8 a, bf16x8 b, f32x4 c) {
    return __builtin_amdgcn_mfma_f32_16x16x32_bf16(a, b, c, 0, 0, 0);
}

__device__ __forceinline__ unsigned short f2bf(float f) {
    unsigned int u = __float_as_uint(f);
    u = (u + 0x7FFFu + ((u >> 16) & 1u)) >> 16;
    return (unsigned short)u;
}
__device__ __forceinline__ float bf2f(unsigned short s) {
    return __uint_as_float(((unsigned int)s) << 16);
}

__device__ __forceinline__ void gload16(const void* g, void* l) {
    __builtin_amdgcn_global_load_lds(
        (const __attribute__((address_space(1))) void*)g,
        (__attribute__((address_space(3))) void*)l, 16, 0, 0);
}

__device__ __forceinline__ float wred(float v) {
#pragma unroll
    for (int off = 32; off > 0; off >>= 1) v += __shfl_down(v, off, 64);
    return v;
}

// pack two positive fp32 -> bf16 pair (round-half-up) in 3 VALU ops
__device__ __forceinline__ unsigned int pack_bf2(float p0, float p1) {
    const unsigned int u0 = __float_as_uint(p0) + 0x8000u;
    const unsigned int u1 = __float_as_uint(p1) + 0x8000u;
    return __builtin_amdgcn_perm(u1, u0, 0x07060302u);  // [u1.hi16 : u0.hi16]
}

// -------------------- fused LayerNorm (blocks 0..NT-1) + weight cvt ----------
__global__ __launch_bounds__(256) void ln_cvt_kernel(
        const float* __restrict__ x, const float* __restrict__ w,
        const float* __restrict__ b, unsigned short* __restrict__ h,
        const float* __restrict__ wq, unsigned short* __restrict__ wqb,
        const float* __restrict__ wo, unsigned short* __restrict__ wob) {
    const int bx = blockIdx.x;
    const int tid = threadIdx.x;
    if (bx >= NT) {
        int i = (bx - NT) * 256 + tid;                    // 0..1048575 float4s
        const float* s; unsigned short* d;
        if (i < 786432) { s = wq; d = wqb; }
        else            { i -= 786432; s = wo; d = wob; }
        const float4 v = ((const float4*)s)[i];
        ((ushort4*)d)[i] = make_ushort4(f2bf(v.x), f2bf(v.y), f2bf(v.z), f2bf(v.w));
        return;
    }
    const float4 v = ((const float4*)(x + (size_t)bx * DD))[tid];
    float s = v.x + v.y + v.z + v.w;
    float ss = v.x*v.x + v.y*v.y + v.z*v.z + v.w*v.w;
    s = wred(s); ss = wred(ss);
    __shared__ float red[8];
    if ((tid & 63) == 0) { red[tid >> 6] = s; red[4 + (tid >> 6)] = ss; }
    __syncthreads();
    s  = red[0] + red[1] + red[2] + red[3];
    ss = red[4] + red[5] + red[6] + red[7];
    const float mu  = s * (1.0f / DD);
    const float inv = rsqrtf(ss * (1.0f / DD) - mu * mu + 1e-5f);
    const float4 wv = ((const float4*)w)[tid];
    const float4 bv = ((const float4*)b)[tid];
    *(ushort4*)(h + (size_t)bx * DD + tid * 4) = make_ushort4(
        f2bf((v.x - mu) * inv * wv.x + bv.x),
        f2bf((v.y - mu) * inv * wv.y + bv.y),
        f2bf((v.z - mu) * inv * wv.z + bv.z),
        f2bf((v.w - mu) * inv * wv.w + bv.w));
}

// -------------------- QKV GEMM: qk[t][2048] + V transposed to vt[B,H,DH,L] ----
__global__ __launch_bounds__(256) void gemm_qkv(
        const unsigned short* __restrict__ A, const unsigned short* __restrict__ B,
        unsigned short* __restrict__ qk, unsigned short* __restrict__ vt) {
    const int K = DD;
    __shared__ unsigned short As[128 * 32];
    __shared__ unsigned short Bs[128 * 32];
    const int tid = threadIdx.x;
    const int w = tid >> 6, lane = tid & 63;
    const int l15 = lane & 15, quad = lane >> 4;
    const int wr = w >> 1, wc = w & 1;
    const int m0 = blockIdx.y << 7, n0 = blockIdx.x << 7;

    const int srow = w * 32 + (lane >> 2);
    const int skel = (lane & 3) << 3;
    const unsigned short* gA = A + (size_t)(m0 + srow) * K + skel;
    const unsigned short* gB = B + (size_t)(n0 + srow) * K + skel;
    unsigned short* lA = &As[w * 1024];
    unsigned short* lB = &Bs[w * 1024];

    f32x4 acc[4][4];
#pragma unroll
    for (int i = 0; i < 4; i++)
#pragma unroll
        for (int j = 0; j < 4; j++) acc[i][j] = (f32x4){0.f, 0.f, 0.f, 0.f};

    for (int k0 = 0; k0 < K; k0 += 32) {
        gload16(gA + k0,                 lA);
        gload16(gA + k0 + (size_t)16*K,  lA + 512);
        gload16(gB + k0,                 lB);
        gload16(gB + k0 + (size_t)16*K,  lB + 512);
        __syncthreads();
        bf16x8 af[4], bg[4];
#pragma unroll
        for (int i = 0; i < 4; i++) {
            af[i] = *(const bf16x8*)&As[(wr*64 + i*16 + l15) * 32 + quad*8];
            bg[i] = *(const bf16x8*)&Bs[(wc*64 + i*16 + l15) * 32 + quad*8];
        }
#pragma unroll
        for (int i = 0; i < 4; i++)
#pragma unroll
            for (int j = 0; j < 4; j++)
                acc[i][j] = mfma16(af[i], bg[j], acc[i][j]);
        __syncthreads();
    }
    if (n0 < D2) {
#pragma unroll
        for (int i = 0; i < 4; i++) {
            const int mrow = m0 + wr*64 + i*16 + quad*4;
#pragma unroll
            for (int j = 0; j < 4; j++) {
                const int ncol = n0 + wc*64 + j*16 + l15;
#pragma unroll
                for (int r = 0; r < 4; r++)
                    qk[(size_t)(mrow + r) * D2 + ncol] = f2bf(acc[i][j][r]);
            }
        }
    } else {
#pragma unroll
        for (int i = 0; i < 4; i++) {
            const int mrow = m0 + wr*64 + i*16 + quad*4;
            const int bb = mrow >> 11, l = mrow & (LL - 1);
#pragma unroll
            for (int j = 0; j < 4; j++) {
                const int nv = n0 + wc*64 + j*16 + l15 - D2;
                const int hh = nv >> 6, dh = nv & 63;
                *(ushort4*)&vt[((size_t)(bb*HH + hh) * DHD + dh) * LL + l] =
                    make_ushort4(f2bf(acc[i][j][0]), f2bf(acc[i][j][1]),
                                 f2bf(acc[i][j][2]), f2bf(acc[i][j][3]));
            }
        }
    }
}

// -------------------- out-proj GEMM: C fp32 = A[M,K] * B[N,K]^T ----------------
__global__ __launch_bounds__(256) void gemm_out(
        const unsigned short* __restrict__ A, const unsigned short* __restrict__ B,
        float* __restrict__ C, int M, int N, int K) {
    __shared__ unsigned short As[128 * 32];
    __shared__ unsigned short Bs[128 * 32];
    const int tid = threadIdx.x;
    const int w = tid >> 6, lane = tid & 63;
    const int l15 = lane & 15, quad = lane >> 4;
    const int wr = w >> 1, wc = w & 1;
    const int m0 = blockIdx.y << 7, n0 = blockIdx.x << 7;
    const int srow = w * 32 + (lane >> 2);
    const int skel = (lane & 3) << 3;
    const unsigned short* gA = A + (size_t)(m0 + srow) * K + skel;
    const unsigned short* gB = B + (size_t)(n0 + srow) * K + skel;
    unsigned short* lA = &As[w * 1024];
    unsigned short* lB = &Bs[w * 1024];
    f32x4 acc[4][4];
#pragma unroll
    for (int i = 0; i < 4; i++)
#pragma unroll
        for (int j = 0; j < 4; j++) acc[i][j] = (f32x4){0.f, 0.f, 0.f, 0.f};
    for (int k0 = 0; k0 < K; k0 += 32) {
        gload16(gA + k0,                 lA);
        gload16(gA + k0 + (size_t)16*K,  lA + 512);
        gload16(gB + k0,                 lB);
        gload16(gB + k0 + (size_t)16*K,  lB + 512);
        __syncthreads();
        bf16x8 af[4], bg[4];
#pragma unroll
        for (int i = 0; i < 4; i++) {
            af[i] = *(const bf16x8*)&As[(wr*64 + i*16 + l15) * 32 + quad*8];
            bg[i] = *(const bf16x8*)&Bs[(wc*64 + i*16 + l15) * 32 + quad*8];
        }
#pragma unroll
        for (int i = 0; i < 4; i++)
#pragma unroll
            for (int j = 0; j < 4; j++)
                acc[i][j] = mfma16(af[i], bg[j], acc[i][j]);
        __syncthreads();
    }
#pragma unroll
    for (int i = 0; i < 4; i++) {
        const int mrow = m0 + wr*64 + i*16 + quad*4;
#pragma unroll
        for (int j = 0; j < 4; j++) {
            const int ncol = n0 + wc*64 + j*16 + l15;
#pragma unroll
            for (int r = 0; r < 4; r++)
                C[(size_t)(mrow + r) * N + ncol] = acc[i][j][r];
        }
    }
}

// -------------------- Q/K LayerNorm + NeoX RoPE: qk -> qarr/karr [B,H,L,DH] ----
// Q pre-scaled by 0.125*log2(e): attention softmax runs in exp2 domain.
__global__ __launch_bounds__(256) void qk_rope_kernel(
        const unsigned short* __restrict__ qk,
        const float* __restrict__ qw, const float* __restrict__ kw,
        unsigned short* __restrict__ qarr, unsigned short* __restrict__ karr) {
    const int t = blockIdx.x;
    const int l = t & (LL - 1), b = t >> 11;
    const int tid = threadIdx.x;
    const unsigned short* base = qk + (size_t)t * D2;
    const ushort4 qu = *(const ushort4*)(base + tid * 4);
    const ushort4 ku = *(const ushort4*)(base + DD + tid * 4);
    const float q[4] = {bf2f(qu.x), bf2f(qu.y), bf2f(qu.z), bf2f(qu.w)};
    const float k[4] = {bf2f(ku.x), bf2f(ku.y), bf2f(ku.z), bf2f(ku.w)};
    float sq = q[0]+q[1]+q[2]+q[3], ssq = q[0]*q[0]+q[1]*q[1]+q[2]*q[2]+q[3]*q[3];
    float sk = k[0]+k[1]+k[2]+k[3], ssk = k[0]*k[0]+k[1]*k[1]+k[2]*k[2]+k[3]*k[3];
    sq = wred(sq); ssq = wred(ssq); sk = wred(sk); ssk = wred(ssk);
    __shared__ float red[16];
    __shared__ float qs[DD], ks[DD];
    const int wid = tid >> 6;
    if ((tid & 63) == 0) { red[wid] = sq; red[4+wid] = ssq; red[8+wid] = sk; red[12+wid] = ssk; }
    __syncthreads();
    sq = red[0]+red[1]+red[2]+red[3];    ssq = red[4]+red[5]+red[6]+red[7];
    sk = red[8]+red[9]+red[10]+red[11];  ssk = red[12]+red[13]+red[14]+red[15];
    const float muq = sq * (1.f/DD), invq = rsqrtf(ssq*(1.f/DD) - muq*muq + 1e-5f);
    const float muk = sk * (1.f/DD), invk = rsqrtf(ssk*(1.f/DD) - muk*muk + 1e-5f);
    const float4 qwv = ((const float4*)qw)[tid];
    const float4 kwv = ((const float4*)kw)[tid];
    const float qwa[4] = {qwv.x, qwv.y, qwv.z, qwv.w};
    const float kwa[4] = {kwv.x, kwv.y, kwv.z, kwv.w};
    float qn[4], kn[4];
#pragma unroll
    for (int e = 0; e < 4; e++) {
        qn[e] = (q[e] - muq) * invq * qwa[e];
        kn[e] = (k[e] - muk) * invk * kwa[e];
    }
    *(float4*)&qs[tid*4] = make_float4(qn[0], qn[1], qn[2], qn[3]);
    *(float4*)&ks[tid*4] = make_float4(kn[0], kn[1], kn[2], kn[3]);
    __syncthreads();
    const int d = tid * 4, j0 = d & 63;
    const bool first = (j0 < 32);
    const int pt = first ? (tid + 8) : (tid - 8);
    const float4 qp4 = *(const float4*)&qs[pt*4];
    const float4 kp4 = *(const float4*)&ks[pt*4];
    const float qb[4] = {qp4.x, qp4.y, qp4.z, qp4.w};
    const float kb[4] = {kp4.x, kp4.y, kp4.z, kp4.w};
    const float lf = (float)l;
    const float QS = 0.125f * 1.44269504088896340736f;   // 1/sqrt(DH) * log2(e)
    unsigned short oq[4], ok[4];
#pragma unroll
    for (int e = 0; e < 4; e++) {
        const float fi   = (float)((j0 & 31) + e);
        const float freq = expf(fi * (-0.28782313662425576f));   // 10000^(-i/32)
        const float ang  = lf * freq;
        const float c = cosf(ang), sn = sinf(ang);
        float vq, vk;
        if (first) { vq = qn[e]*c - qb[e]*sn; vk = kn[e]*c - kb[e]*sn; }
        else       { vq = qn[e]*c + qb[e]*sn; vk = kn[e]*c + kb[e]*sn; }
        oq[e] = f2bf(vq * QS);
        ok[e] = f2bf(vk);
    }
    const int hh = tid >> 4;
    const int dh = (tid * 4) & 63;
    const size_t ro = ((size_t)(b*HH + hh) * LL + l) * DHD + dh;
    *(ushort4*)(qarr + ro) = make_ushort4(oq[0], oq[1], oq[2], oq[3]);
    *(ushort4*)(karr + ro) = make_ushort4(ok[0], ok[1], ok[2], ok[3]);
}

// -------------------- MFMA flash attention, kv-split=2, fixed-shift softmax ----
// grid 1024: x -> (g = (bh,split), qblk); 16 qblks of one g share an XCD.
// Wave owns 32 q-rows. Softmax: p = exp2(qk*scale - 64) -- shift folded into
// MFMA C-init; no max/rescale; partials (raw o bf16, l fp32) merged later.
__global__ __launch_bounds__(256, 4) void attn_kernel(
        const unsigned short* __restrict__ qarr,
        const unsigned short* __restrict__ karr,
        const unsigned short* __restrict__ vt,
        unsigned short* __restrict__ opart,   // [2][NT][DD] bf16 raw numerators
        float* __restrict__ lpart) {          // [2][B*H][L] fp32 denominators
    const int x = blockIdx.x;
    const int g  = (x & 7) | ((x >> 7) << 3);     // 0..63 = (bh, split)
    const int qblk = (x >> 3) & 15;
    const int s = g & 1, bh = g >> 1;
    const int b = bh >> 4, h = bh & 15;
    const int q0 = qblk << 7;
    const int kvbase = s << 10;                    // split kv range: 1024 each
    const int tid = threadIdx.x, w = tid >> 6, lane = tid & 63;
    const int l15 = lane & 15, quad = lane >> 4;

    __shared__ unsigned short Ks[64 * 64];
    __shared__ unsigned short Vs[64 * 64];
    __shared__ unsigned short Pw[4][2][16][72];

    const unsigned short* kbase = karr + ((size_t)bh * LL + kvbase) * DHD;
    const unsigned short* vbase = vt   + (size_t)bh * DHD * LL + kvbase;

    // Q frags (B-operand), persistent
    bf16x8 qf[2][2];
    {
        const unsigned short* qp = qarr + ((size_t)bh*LL + q0 + w*32 + l15) * DHD + quad*8;
#pragma unroll
        for (int qt = 0; qt < 2; qt++)
#pragma unroll
            for (int c = 0; c < 2; c++)
                qf[qt][c] = *(const bf16x8*)(qp + qt*16*DHD + c*32);
    }

    bf16x8 ones;
#pragma unroll
    for (int i = 0; i < 8; i++) ones[i] = (__bf16)1.0f;

    const int r8 = lane >> 3, sc = lane & 7;
    f32x4 o[2][4], lacc[2];
#pragma unroll
    for (int qt = 0; qt < 2; qt++) {
        lacc[qt] = (f32x4){0.f, 0.f, 0.f, 0.f};
#pragma unroll
        for (int nt = 0; nt < 4; nt++) o[qt][nt] = (f32x4){0.f, 0.f, 0.f, 0.f};
    }

    // stage tile 0
#pragma unroll
    for (int rd = 0; rd < 2; rd++) {
        const int row = w*8 + rd*32 + r8;
        const int chunk = sc ^ (row & 7);
        gload16(kbase + (size_t)row * DHD + chunk*8, (char*)Ks + w*1024 + rd*4096);
        gload16(vbase + (size_t)row * LL + chunk*8,  (char*)Vs + w*1024 + rd*4096);
    }

    for (int kt = 0; kt < 16; kt++) {
        __syncthreads();                    // stage(kt) drained
        bf16x8 kf[4][2], vf[4][2];
#pragma unroll
        for (int t = 0; t < 4; t++)
#pragma unroll
            for (int c = 0; c < 2; c++) {
                const int slot = (quad + c*4) ^ (l15 & 7);
                kf[t][c] = *(const bf16x8*)&Ks[(t*16 + l15) * DHD + slot*8];
                vf[t][c] = *(const bf16x8*)&Vs[(t*16 + l15) * DHD + slot*8];
            }
        __syncthreads();                    // reads done; safe to overwrite
        if (kt + 1 < 16) {
#pragma unroll
            for (int rd = 0; rd < 2; rd++) {
                const int row = w*8 + rd*32 + r8;
                const int chunk = sc ^ (row & 7);
                gload16(kbase + ((size_t)((kt+1)*64 + row)) * DHD + chunk*8,
                        (char*)Ks + w*1024 + rd*4096);
                gload16(vbase + (size_t)row * LL + (kt+1)*64 + chunk*8,
                        (char*)Vs + w*1024 + rd*4096);
            }
        }

#pragma unroll
        for (int qt = 0; qt < 2; qt++) {
            // S^T = K.Q^T - 64 (fixed softmax shift via C-init)
            f32x4 st[4];
#pragma unroll
            for (int t = 0; t < 4; t++) {
                f32x4 z = (f32x4){-64.f, -64.f, -64.f, -64.f};
                z = mfma16(kf[t][0], qf[qt][0], z);
                z = mfma16(kf[t][1], qf[qt][1], z);
                st[t] = z;
            }
            // p = exp2(st); pack round-half-up; wave-private LDS relayout
#pragma unroll
            for (int t = 0; t < 4; t++) {
                const float p0 = __builtin_amdgcn_exp2f(st[t][0]);
                const float p1 = __builtin_amdgcn_exp2f(st[t][1]);
                const float p2 = __builtin_amdgcn_exp2f(st[t][2]);
                const float p3 = __builtin_amdgcn_exp2f(st[t][3]);
                uint2 pk;
                pk.x = pack_bf2(p0, p1);
                pk.y = pack_bf2(p2, p3);
                *(uint2*)&Pw[w][qt][l15][t*16 + quad*4] = pk;
            }
            const bf16x8 ap0 = *(const bf16x8*)&Pw[w][qt][l15][quad*8];
            const bf16x8 ap1 = *(const bf16x8*)&Pw[w][qt][l15][32 + quad*8];
            lacc[qt] = mfma16(ap0, ones, lacc[qt]);
            lacc[qt] = mfma16(ap1, ones, lacc[qt]);
#pragma unroll
            for (int nt = 0; nt < 4; nt++) {
                f32x4 t0 = o[qt][nt];
                t0 = mfma16(ap0, vf[nt][0], t0);
                t0 = mfma16(ap1, vf[nt][1], t0);
                o[qt][nt] = t0;
            }
        }
    }

    unsigned short* op = opart + (size_t)s * NT * DD;
#pragma unroll
    for (int qt = 0; qt < 2; qt++) {
#pragma unroll
        for (int r = 0; r < 4; r++) {
            const int qrow = q0 + w*32 + qt*16 + quad*4 + r;
            const size_t token = (size_t)b * LL + qrow;
#pragma unroll
            for (int nt = 0; nt < 4; nt++)
                op[token * DD + h*DHD + nt*16 + l15] = f2bf(o[qt][nt][r]);
        }
        if (l15 == 0) {
#pragma unroll
            for (int r = 0; r < 4; r++)
                lpart[((size_t)s * BB*HH + bh) * LL + q0 + w*32 + qt*16 + quad*4 + r] =
                    lacc[qt][r];
        }
    }
}

// -------------------- combine kv-split partials -> ctx bf16 --------------------
__global__ __launch_bounds__(256) void combine_kernel(
        const unsigned short* __restrict__ opart, const float* __restrict__ lpart,
        unsigned short* __restrict__ ctx) {
    const int token = blockIdx.x;
    const int tid = threadIdx.x;
    const int b = token >> 11, l = token & (LL - 1);
    const int h = tid >> 4;
    const size_t idx = (size_t)token * DD + tid * 4;
    const ushort4 a = *(const ushort4*)(opart + idx);
    const ushort4 c = *(const ushort4*)(opart + (size_t)NT * DD + idx);
    const float l1 = lpart[((size_t)(b*HH + h)) * LL + l];
    const float l2 = lpart[((size_t)BB*HH*LL) + ((size_t)(b*HH + h)) * LL + l];
    const float inv = 1.0f / (l1 + l2);
    *(ushort4*)(ctx + idx) = make_ushort4(
        f2bf((bf2f(a.x) + bf2f(c.x)) * inv),
        f2bf((bf2f(a.y) + bf2f(c.y)) * inv),
        f2bf((bf2f(a.z) + bf2f(c.z)) * inv),
        f2bf((bf2f(a.w) + bf2f(c.w)) * inv));
}

extern "C" void kernel_launch(void* const* d_in, const int* in_sizes, int n_in,
                              void* d_out, int out_size, void* d_ws, size_t ws_size,
                              hipStream_t stream) {
    const float* x      = (const float*)d_in[0];
    const float* ln_w   = (const float*)d_in[1];
    const float* ln_b   = (const float*)d_in[2];
    const float* w_qkv  = (const float*)d_in[3];
    const float* q_ln_w = (const float*)d_in[4];
    const float* k_ln_w = (const float*)d_in[5];
    const float* w_out  = (const float*)d_in[6];
    float* out = (float*)d_out;

    // workspace map (48 MB), lifetime-aliased:
    //  [0,8M)   h bf16 -> karr (rope) -> ctx (combine)
    //  [8,24M)  qk bf16 -> opart bf16 [2][NT][DD] (attn)
    //  [24,32M) vt bf16 [B,H,DH,L]
    //  [32,40M) qarr bf16 [B,H,L,DH]
    //  [40,46M) w_qkv bf16 -> lpart fp32 [2][BH][L] (512KB, attn)
    //  [46,48M) w_out bf16
    char* ws = (char*)d_ws;
    unsigned short* hb    = (unsigned short*)ws;
    unsigned short* karr  = (unsigned short*)ws;
    unsigned short* ctxb  = (unsigned short*)ws;
    unsigned short* qk    = (unsigned short*)(ws + ((size_t)8  << 20));
    unsigned short* opart = (unsigned short*)(ws + ((size_t)8  << 20));
    unsigned short* vtp   = (unsigned short*)(ws + ((size_t)24 << 20));
    unsigned short* qarr  = (unsigned short*)(ws + ((size_t)32 << 20));
    unsigned short* wqb   = (unsigned short*)(ws + ((size_t)40 << 20));
    float*          lpart = (float*)(ws + ((size_t)40 << 20));
    unsigned short* wob   = (unsigned short*)(ws + ((size_t)46 << 20));

    ln_cvt_kernel<<<NT + 4096, 256, 0, stream>>>(x, ln_w, ln_b, hb,
                                                 w_qkv, wqb, w_out, wob);
    gemm_qkv<<<dim3(D3/128, NT/128), 256, 0, stream>>>(hb, wqb, qk, vtp);
    qk_rope_kernel<<<NT, 256, 0, stream>>>(qk, q_ln_w, k_ln_w, qarr, karr);
    attn_kernel<<<1024, 256, 0, stream>>>(qarr, karr, vtp, opart, lpart);
    combine_kernel<<<NT, 256, 0, stream>>>(opart, lpart, ctxb);
    gemm_out<<<dim3(DD/128, NT/128), 256, 0, stream>>>(ctxb, wob, out, NT, DD, DD);
}